// Round 1
// baseline (395.872 us; speedup 1.0000x reference)
//
#include <hip/hip_runtime.h>
#include <hip/hip_bf16.h>

// GraphSAGE-LSTM aggregator, MI355X (gfx950).
// B=16384, T=25, D=128, U=128, 4U=512.
// Kernel 1 (prep): pack lstm_W, lstm_U, node_weights into bf16 MFMA B-fragments
//   (permuted columns: wave w owns units [w*16, w*16+16), all 4 gates) in d_ws.
// Kernel 2 (lstm): 256 blocks x 512 thr (8 waves), 64 rows/block, 1 block/CU.
//   Per step: z = b + x_t@W + h@U via mfma_f32_16x16x32_bf16 (fp32 acc),
//   gates fp32 in-register, c fp32 persistent, h -> LDS bf16 (XOR-swizzled).
//   x_{t+1} gather (features via neighbours idx) prefetched under MFMA phase.
//   Epilogue: from_self = node_feat @ node_weights, out = relu((s+h)/2).

typedef __bf16 bf16;
typedef __bf16 bf16x8 __attribute__((ext_vector_type(8)));
typedef float f32x4 __attribute__((ext_vector_type(4)));

__device__ __forceinline__ float fast_sig(float x) {
  float e = __builtin_amdgcn_exp2f(-1.442695041f * x);
  return __builtin_amdgcn_rcpf(1.0f + e);
}
__device__ __forceinline__ float fast_tanh(float x) {
  float e = __builtin_amdgcn_exp2f(-2.885390082f * x);
  return (1.0f - e) * __builtin_amdgcn_rcpf(1.0f + e);
}
__device__ __forceinline__ f32x4 splat4(float x) {
  f32x4 v; v[0] = x; v[1] = x; v[2] = x; v[3] = x; return v;
}
__device__ __forceinline__ bf16x8 pack8(float4 a, float4 b) {
  bf16x8 v;
  v[0] = (bf16)a.x; v[1] = (bf16)a.y; v[2] = (bf16)a.z; v[3] = (bf16)a.w;
  v[4] = (bf16)b.x; v[5] = (bf16)b.y; v[6] = (bf16)b.z; v[7] = (bf16)b.w;
  return v;
}

// ---------------- prep: fragment-pack weights into ws (bf16) ----------------
// ws layout (bf16 elems):
//   [0, 65536)        W frags: frag f = (w*4+g)*4+kt, elem = f*512 + lane*8 + j
//   [65536, 131072)   U frags, same layout
//   [131072, 147456)  node_weights frags: f = w*4+kt
// Fragment semantics (B operand of 16x16x32): lane supplies
//   B[k = kt*32 + (lane>>4)*8 + j][col], col = g*128 + w*16 + (lane&15).
__global__ void prep_kernel(const float* __restrict__ W, const float* __restrict__ U,
                            const float* __restrict__ NW, bf16* __restrict__ ws) {
  int idx = blockIdx.x * 256 + threadIdx.x;  // 576*256 = 147456 exactly
  if (idx < 131072) {
    const float* __restrict__ src = (idx < 65536) ? W : U;
    int r = idx & 65535;
    int f = r >> 9, lane = (r >> 3) & 63, j = r & 7;
    int kt = f & 3, g = (f >> 2) & 3, w = f >> 4;
    int k = kt * 32 + (lane >> 4) * 8 + j;
    int col = g * 128 + w * 16 + (lane & 15);
    ws[idx] = (bf16)src[k * 512 + col];
  } else {
    int r = idx - 131072;
    int f = r >> 9, lane = (r >> 3) & 63, j = r & 7;
    int kt = f & 3, w = f >> 2;
    int k = kt * 32 + (lane >> 4) * 8 + j;
    int col = w * 16 + (lane & 15);
    ws[idx] = (bf16)NW[k * 128 + col];
  }
}

// ---------------- fused LSTM aggregator ----------------
__global__ __launch_bounds__(512, 2)
void lstm_kernel(const float* __restrict__ feats, const int* __restrict__ node,
                 const int* __restrict__ neigh, const float* __restrict__ bias,
                 const bf16* __restrict__ wsf, float* __restrict__ out) {
  __shared__ char xb[16384];  // x tile [64 rows][128] bf16, XOR-swizzled
  __shared__ char hb[16384];  // h tile [64 rows][128] bf16, XOR-swizzled

  const int tid  = threadIdx.x;
  const int lane = tid & 63;
  const int wv   = tid >> 6;       // wave id = unit group (16 units each)
  const int l15  = lane & 15;
  const int lhi  = lane >> 4;
  const int b0   = blockIdx.x * 64;
  const float4* __restrict__ feats4 = (const float4*)feats;

  // Persistent U fragments in registers (64 VGPR), loaded once.
  bf16x8 uf[4][4];
#pragma unroll
  for (int g = 0; g < 4; ++g)
#pragma unroll
    for (int kt = 0; kt < 4; ++kt)
      uf[g][kt] = *(const bf16x8*)(wsf + 65536 + (((wv * 4 + g) * 4 + kt) << 9) + (lane << 3));

  float bb[4];
#pragma unroll
  for (int g = 0; g < 4; ++g) bb[g] = bias[g * 128 + wv * 16 + l15];

  f32x4 cc[4];  // cell state: row = m*16 + lhi*4 + r, unit = wv*16 + l15
#pragma unroll
  for (int m = 0; m < 4; ++m) cc[m] = splat4(0.0f);

  // Gather mapping: thread covers row gr, 16 consecutive feature elems.
  const int gr = tid >> 3;          // 0..63
  const int gq = tid & 7;           // 64B chunk within row
  const int xsw = (gr & 7) << 4;
  const int xbase = gr * 256 + gq * 32;

  // x_0
  {
    int ni = neigh[(b0 + gr) * 25];
    float4 a = feats4[ni * 32 + gq * 4 + 0];
    float4 b = feats4[ni * 32 + gq * 4 + 1];
    float4 c = feats4[ni * 32 + gq * 4 + 2];
    float4 d = feats4[ni * 32 + gq * 4 + 3];
    *(bf16x8*)(xb + (xbase ^ xsw))        = pack8(a, b);
    *(bf16x8*)(xb + ((xbase + 16) ^ xsw)) = pack8(c, d);
  }
  __syncthreads();

  f32x4 acc[4][4];                 // [gate][Mtile]
  const int asw = (l15 & 7) << 4;  // A-frag row swizzle (row&7 == l15&7)

  auto mfma_phase = [&](bool withH) {
#pragma unroll
    for (int kt = 0; kt < 4; ++kt) {
      bf16x8 wfr[4];
#pragma unroll
      for (int g = 0; g < 4; ++g)
        wfr[g] = *(const bf16x8*)(wsf + (((wv * 4 + g) * 4 + kt) << 9) + (lane << 3));
      bf16x8 xa[4];
#pragma unroll
      for (int m = 0; m < 4; ++m)
        xa[m] = *(const bf16x8*)(xb + (((m * 16 + l15) * 256 + (kt * 4 + lhi) * 16) ^ asw));
#pragma unroll
      for (int g = 0; g < 4; ++g)
#pragma unroll
        for (int m = 0; m < 4; ++m)
          acc[g][m] = __builtin_amdgcn_mfma_f32_16x16x32_bf16(xa[m], wfr[g], acc[g][m], 0, 0, 0);
      if (withH) {
        bf16x8 ha[4];
#pragma unroll
        for (int m = 0; m < 4; ++m)
          ha[m] = *(const bf16x8*)(hb + (((m * 16 + l15) * 256 + (kt * 4 + lhi) * 16) ^ asw));
#pragma unroll
        for (int g = 0; g < 4; ++g)
#pragma unroll
          for (int m = 0; m < 4; ++m)
            acc[g][m] = __builtin_amdgcn_mfma_f32_16x16x32_bf16(ha[m], uf[g][kt], acc[g][m], 0, 0, 0);
      }
    }
  };

#pragma unroll 1
  for (int t = 0; t < 24; ++t) {
    // prefetch x_{t+1}: lands under MFMA phase, written after the barrier
    int ni = neigh[(b0 + gr) * 25 + t + 1];
    float4 pa = feats4[ni * 32 + gq * 4 + 0];
    float4 pb = feats4[ni * 32 + gq * 4 + 1];
    float4 pc = feats4[ni * 32 + gq * 4 + 2];
    float4 pd = feats4[ni * 32 + gq * 4 + 3];

#pragma unroll
    for (int g = 0; g < 4; ++g) {
      f32x4 bi = splat4(bb[g]);
#pragma unroll
      for (int m = 0; m < 4; ++m) acc[g][m] = bi;
    }

    if (t == 0) mfma_phase(false); else mfma_phase(true);
    __syncthreads();  // all reads of xb/hb done

    *(bf16x8*)(xb + (xbase ^ xsw))        = pack8(pa, pb);
    *(bf16x8*)(xb + ((xbase + 16) ^ xsw)) = pack8(pc, pd);

#pragma unroll
    for (int m = 0; m < 4; ++m)
#pragma unroll
      for (int r = 0; r < 4; ++r) {
        float iv = fast_sig(acc[0][m][r]);
        float fv = fast_sig(acc[1][m][r]);
        float gv = fast_tanh(acc[2][m][r]);
        float ov = fast_sig(acc[3][m][r]);
        float cv = fv * cc[m][r] + iv * gv;
        cc[m][r] = cv;
        float hv = ov * fast_tanh(cv);
        int row = m * 16 + lhi * 4 + r;
        *(bf16*)(hb + ((row * 256 + (wv * 16 + l15) * 2) ^ ((row & 7) << 4))) = (bf16)hv;
      }
    __syncthreads();  // new x/h visible
  }

  // ----- step 24 (peeled): prefetch NODE features instead of neighbours -----
  float hl[4][4];
  {
    int ni = node[b0 + gr];
    float4 pa = feats4[ni * 32 + gq * 4 + 0];
    float4 pb = feats4[ni * 32 + gq * 4 + 1];
    float4 pc = feats4[ni * 32 + gq * 4 + 2];
    float4 pd = feats4[ni * 32 + gq * 4 + 3];

#pragma unroll
    for (int g = 0; g < 4; ++g) {
      f32x4 bi = splat4(bb[g]);
#pragma unroll
      for (int m = 0; m < 4; ++m) acc[g][m] = bi;
    }
    mfma_phase(true);
    __syncthreads();

    *(bf16x8*)(xb + (xbase ^ xsw))        = pack8(pa, pb);  // node feats
    *(bf16x8*)(xb + ((xbase + 16) ^ xsw)) = pack8(pc, pd);

#pragma unroll
    for (int m = 0; m < 4; ++m)
#pragma unroll
      for (int r = 0; r < 4; ++r) {
        float iv = fast_sig(acc[0][m][r]);
        float fv = fast_sig(acc[1][m][r]);
        float gv = fast_tanh(acc[2][m][r]);
        float ov = fast_sig(acc[3][m][r]);
        float cv = fv * cc[m][r] + iv * gv;
        hl[m][r] = ov * fast_tanh(cv);
      }
    __syncthreads();  // node feats visible in xb
  }

  // ----- from_self = node_feat @ node_weights; out = relu((s + h)/2) -----
  {
    bf16x8 nwf[4];
#pragma unroll
    for (int kt = 0; kt < 4; ++kt)
      nwf[kt] = *(const bf16x8*)(wsf + 131072 + ((wv * 4 + kt) << 9) + (lane << 3));
    f32x4 accs[4];
#pragma unroll
    for (int m = 0; m < 4; ++m) accs[m] = splat4(0.0f);
#pragma unroll
    for (int kt = 0; kt < 4; ++kt) {
      bf16x8 xa[4];
#pragma unroll
      for (int m = 0; m < 4; ++m)
        xa[m] = *(const bf16x8*)(xb + (((m * 16 + l15) * 256 + (kt * 4 + lhi) * 16) ^ asw));
#pragma unroll
      for (int m = 0; m < 4; ++m)
        accs[m] = __builtin_amdgcn_mfma_f32_16x16x32_bf16(xa[m], nwf[kt], accs[m], 0, 0, 0);
    }
#pragma unroll
    for (int m = 0; m < 4; ++m)
#pragma unroll
      for (int r = 0; r < 4; ++r) {
        int row = m * 16 + lhi * 4 + r;
        float v = (accs[m][r] + hl[m][r]) * 0.5f;
        out[(b0 + row) * 128 + wv * 16 + l15] = v > 0.0f ? v : 0.0f;
      }
  }
}

extern "C" void kernel_launch(void* const* d_in, const int* in_sizes, int n_in,
                              void* d_out, int out_size, void* d_ws, size_t ws_size,
                              hipStream_t stream) {
  const float* feats = (const float*)d_in[0];   // 100000 x 128
  const int*   node  = (const int*)d_in[1];     // 16384 x 1
  const int*   neigh = (const int*)d_in[2];     // 16384 x 25
  const float* nw    = (const float*)d_in[3];   // 128 x 128
  const float* W     = (const float*)d_in[4];   // 128 x 512
  const float* U     = (const float*)d_in[5];   // 128 x 512
  const float* b     = (const float*)d_in[6];   // 512
  bf16* ws = (bf16*)d_ws;                       // needs 294912 B
  float* out = (float*)d_out;                   // 16384 x 128

  prep_kernel<<<576, 256, 0, stream>>>(W, U, nw, ws);
  lstm_kernel<<<256, 512, 0, stream>>>(feats, node, neigh, b, ws, out);
}